// Round 12
// baseline (177.596 us; speedup 1.0000x reference)
//
#include <hip/hip_runtime.h>
#include <hip/hip_bf16.h>

typedef unsigned short u16;
typedef __attribute__((ext_vector_type(8))) __bf16 bf16x8;
typedef __attribute__((ext_vector_type(4))) float f32x4;
typedef __attribute__((ext_vector_type(16))) float f32x16;
typedef __attribute__((ext_vector_type(8))) u16 u16x8;

#define BATCH 2
#define SEQ   2048
#define DIM   1024
#define HEADS 16
#define HDIM  64

// 0.125 (1/sqrt(64)) * log2(e): folded into Q so attn uses bare exp2
#define QSCALE 0.18033688011112042f

__device__ __forceinline__ float bf2f(u16 u) {
  union { unsigned int u; float f; } v; v.u = ((unsigned int)u) << 16; return v.f;
}
__device__ __forceinline__ u16 f2bf(float f) {
  union { float f; unsigned int u; } v; v.f = f;
  unsigned int r = v.u + 0x7fffu + ((v.u >> 16) & 1u);
  return (u16)(r >> 16);
}
// pack two fp32 -> bf16x2 (RNE) in one HW instr (v_cvt_pk_bf16_f32)
__device__ __forceinline__ unsigned int pk2(float a, float b) {
  union { __hip_bfloat162 h2; unsigned int u; } v;
  v.h2 = __float22bfloat162_rn(float2{a, b});
  return v.u;
}
// gfx950 two-register half-swap (VALU): a.lanes[32..63] <-> b.lanes[0..31]
__device__ __forceinline__ void pl32(unsigned &a, unsigned &b) {
  asm volatile("v_permlane32_swap_b32 %0, %1" : "+v"(a), "+v"(b));
}

// async global->LDS DMA, 16 B per lane; LDS dest = wave-uniform base + lane*16
__device__ __forceinline__ void async16(u16* lds, const u16* g) {
  __builtin_amdgcn_global_load_lds(
      (__attribute__((address_space(1))) void*)(void*)(g),
      (__attribute__((address_space(3))) void*)(lds), 16, 0, 0);
}

// ---------------------------------------------------------------------------
// Kernel 0: one-shot fp32 -> bf16 (RNE) conversion of x, Wq, Wk, Wv.
// ---------------------------------------------------------------------------
#define XG  524288   /* x groups of 8 */
#define WG  131072   /* per-W groups of 8 */
extern "C" __global__ __launch_bounds__(256)
void convert_all(const float* __restrict__ x,  const float* __restrict__ wq,
                 const float* __restrict__ wk, const float* __restrict__ wv,
                 u16* __restrict__ xbf, u16* __restrict__ wbf)
{
  const int g = blockIdx.x * 256 + threadIdx.x;
  const float* src; u16* dst; size_t off;
  if (g < XG)               { src = x;  dst = xbf;                 off = (size_t)g; }
  else if (g < XG + WG)     { src = wq; dst = wbf;                 off = (size_t)(g - XG); }
  else if (g < XG + 2 * WG) { src = wk; dst = wbf + DIM * DIM;     off = (size_t)(g - XG - WG); }
  else                      { src = wv; dst = wbf + 2 * DIM * DIM; off = (size_t)(g - XG - 2 * WG); }
  f32x4 a = *(const f32x4*)(src + off * 8);
  f32x4 b = *(const f32x4*)(src + off * 8 + 4);
  u16x8 o;
#pragma unroll
  for (int i = 0; i < 4; ++i) { o[i] = f2bf(a[i]); o[4 + i] = f2bf(b[i]); }
  *(u16x8*)(dst + off * 8) = o;
}

// ---------------------------------------------------------------------------
// Kernel 1: QKV projection — round-18: 128x64 tiles for occupancy.
// R7 counters (only qkv snapshot): MfmaUtil 17.5%, VALUBusy 11%, Occ 14% —
// latency-bound; grid 768 = EXACTLY 3 blocks/CU was the limiter (VGPR caps
// at 16 waves, LDS at 3 blocks — the grid is the binding constraint).
// This round: tile 128(M)x64(N), grid 1536, LDS 3x(8K+4K)=36 KB -> 4
// resident blocks/CU (144<=160 KB), grid 6/CU keeps CUs fed as blocks
// retire. Per wave-iter: 8 MFMA + 6 ds_read_b128 + 3 DMA (was 16/8/4 at
// 2x the tile). Proven K-loop kept: triple buffer, prefetch distance 2,
// bottom wait vmcnt(3) (tile t+1's 3 DMAs retire, t+2's stay in flight).
// XCD cluster (1536): XCD p owns m-group p>>1 (8 panels x 128) x n-half
// p&1 (8 blocks x 64) x 3 which -> in-flight A 2 MB + B 1 MB < 4 MB L2.
// Chunk swizzle (R11) kept on both A and B.
// grid: flat 1536  block: 256
// which==0 -> Q(*QSCALE) [b][h][s][d]; 1 -> K [b][h][s][d]; 2 -> V^T [b][h][d][s]
// ---------------------------------------------------------------------------
extern "C" __global__ __launch_bounds__(256)
void qkv_gemm(const u16* __restrict__ xbf, const u16* __restrict__ wbf,
              const float* __restrict__ bq, const float* __restrict__ bk,
              const float* __restrict__ bv,
              u16* __restrict__ qo, u16* __restrict__ ko, u16* __restrict__ vto)
{
  __shared__ alignas(16) u16 Albs[3][128 * 32];  // 24 KB
  __shared__ alignas(16) u16 Blbs[3][64 * 32];   // 12 KB

  // XCD-clustered decode (1536 blocks): p = XCD, q = wg>>3 in [0,192)
  const int wg = blockIdx.x;
  const int p  = wg & 7;
  const int q  = wg >> 3;              // 0..191
  const int which = q >> 6;            // 0..2
  const int r  = q & 63;               // 8 m x 8 n
  const int mBase = ((p >> 1) * 8 + (r >> 3)) * 128;
  const int nBase = ((p & 1) * 8 + (r & 7)) * 64;

  const u16* Wb = wbf + (size_t)which * DIM * DIM;
  const float* bias = (which == 0) ? bq : (which == 1) ? bk : bv;

  const int lane = threadIdx.x & 63;
  const int wave = threadIdx.x >> 6;
  const int l16  = lane & 15;
  const int quad = lane >> 4;
  const int lrow = lane >> 2;                      // 16 rows per DMA instr
  const int lcol = ((lane & 3) ^ ((lane >> 3) & 3)) * 8;  // swizzled src chunk
  const int rkey = (l16 >> 1) & 3;                 // read-side chunk XOR key

  const int mw = (wave >> 1) * 64;   // wave's 64x32 quadrant
  const int nw = (wave & 1) * 32;

  f32x4 acc[4][2] = {};

  // stage K-tile kt (32 wide) into buffer bidx: 3 DMA instrs per wave
  // (A: 8 groups of 16 rows -> wave*2+pp; B: 4 groups -> wave)
  auto stage = [&](int bidx, int kt) {
    const int k0 = kt * 32;
#pragma unroll
    for (int pp = 0; pp < 2; ++pp) {
      const int r16 = wave * 2 + pp;                 // wave-uniform
      const int row = r16 * 16 + lrow;
      async16(&Albs[bidx][r16 * 512], xbf + (size_t)(mBase + row) * DIM + k0 + lcol);
    }
    async16(&Blbs[bidx][wave * 512], Wb + (size_t)(nBase + wave * 16 + lrow) * DIM + k0 + lcol);
  };
  // one BK=32 step of MFMA from buffer bidx
  auto comp = [&](int bidx) {
    bf16x8 af[4], bfr[2];
#pragma unroll
    for (int i = 0; i < 4; ++i)
      af[i]  = *(const bf16x8*)&Albs[bidx][(mw + i * 16 + l16) * 32 + ((quad ^ rkey) * 8)];
#pragma unroll
    for (int i = 0; i < 2; ++i)
      bfr[i] = *(const bf16x8*)&Blbs[bidx][(nw + i * 16 + l16) * 32 + ((quad ^ rkey) * 8)];
    __builtin_amdgcn_s_setprio(1);
#pragma unroll
    for (int mi = 0; mi < 4; ++mi)
#pragma unroll
      for (int ni = 0; ni < 2; ++ni)
        acc[mi][ni] = __builtin_amdgcn_mfma_f32_16x16x32_bf16(af[mi], bfr[ni], acc[mi][ni], 0, 0, 0);
    __builtin_amdgcn_s_setprio(0);
  };

  // ---- prologue: stage tiles 0,1; wait tile 0 only (tile 1 in flight) ----
  stage(0, 0);
  stage(1, 1);
  asm volatile("s_waitcnt vmcnt(3)" ::: "memory");
  __syncthreads();

  int i0 = 0, i1 = 1, i2 = 2;   // rotating buffers: tile t, t+1, t+2
  for (int t = 0; t < 32; ++t) {
    if (t < 30) stage(i2, t + 2);
    comp(i0);
    // bottom wait: tile t+1 landed, keep tile t+2's 3 DMAs in flight
    if (t < 30)      asm volatile("s_waitcnt vmcnt(3)" ::: "memory");
    else if (t < 31) asm volatile("s_waitcnt vmcnt(0)" ::: "memory");
    if (t < 31) __syncthreads();
    const int tmp = i0; i0 = i1; i1 = i2; i2 = tmp;
  }

  const float oscale = (which == 0) ? QSCALE : 1.0f;
#pragma unroll
  for (int ni = 0; ni < 2; ++ni) {
    const int n = nBase + nw + ni * 16 + l16;   // C/D col = lane&15
    const float bval = bias[n];
    const int h = n >> 6, d = n & 63;
#pragma unroll
    for (int mi = 0; mi < 4; ++mi) {
      const int m0 = mBase + mw + mi * 16 + quad * 4;  // row = quad*4+r
      if (which == 2) {
        // s = m0..m0+3 consecutive -> one 8 B store of 4 packed bf16
        const int bi = m0 >> 11, s = m0 & 2047;
        uint2 pkv;
        pkv.x = pk2(acc[mi][ni][0] + bval, acc[mi][ni][1] + bval);
        pkv.y = pk2(acc[mi][ni][2] + bval, acc[mi][ni][3] + bval);
        *(uint2*)&vto[((size_t)(bi * HEADS + h) * HDIM + d) * SEQ + s] = pkv;
      } else {
        u16* dst = (which == 0) ? qo : ko;
#pragma unroll
        for (int rr = 0; rr < 4; ++rr) {
          const int m = m0 + rr;
          const int bi = m >> 11, s = m & 2047;
          dst[((size_t)(bi * HEADS + h) * SEQ + s) * HDIM + d] =
              f2bf((acc[mi][ni][rr] + bval) * oscale);
        }
      }
    }
  }
}

// ---------------------------------------------------------------------------
// Kernel 2: flash attention — EXACT round-13/R8 form (best measured:
// 50.8-52.8 us): 32x32x16 MFMA, key-half wave split, 8 waves,
// triple-buffered K/V, permlane transpose, XCD-clustered flat grid,
// setprio around MFMA. Attn DS is at its structural floor for this tiling
// (1 LDS fragment per MFMA); padding/reg-staging variants all regressed.
// grid: flat 512  block: 512
// ---------------------------------------------------------------------------
extern "C" __global__ __launch_bounds__(512)
void attn(const u16* __restrict__ q, const u16* __restrict__ k,
          const u16* __restrict__ vt, float* __restrict__ out)
{
  __shared__ alignas(16) u16 KV[3][8192];   // per buf: K [0,4096), V [4096,8192)
  __shared__ float Lred[8][32];             // per-wave lsum, 1 KB

  const int lane = threadIdx.x & 63;
  const int wave = threadIdx.x >> 6;  // 0..7
  const int qg   = wave >> 1;         // q-group (32 rows)
  const int wh   = wave & 1;          // key half: keys wh*32..wh*32+31
  const int l32  = lane & 31;
  const int khi  = lane >> 5;         // hi bit of lane
  const int e7   = lane & 7;          // row&7 for K/V fragment reads
  const int r8   = lane >> 3;         // DMA: row within 8-row group
  const int sl   = lane & 7;          // DMA: 16B slot within row
  const int jsw  = sl ^ (r8 & 7);     // swizzled source chunk for DMA

  // XCD-clustered decode: wgid = (hb&7) + 8*qb + 128*(hb>>3)
  const int wg = blockIdx.x;
  const int hb = (wg & 7) | ((wg >> 7) << 3);   // h + 16*b, 0..31
  const int qb = (wg >> 3) & 15;
  const int h  = hb & 15;
  const int b  = hb >> 4;
  const int qbase = qb * 128 + qg * 32;

  const u16* qh  = q  + (size_t)(b * HEADS + h) * SEQ * HDIM;
  const u16* kh  = k  + (size_t)(b * HEADS + h) * SEQ * HDIM;
  const u16* vth = vt + (size_t)(b * HEADS + h) * HDIM * SEQ;

  // Q B-frags (32x32x16): lane -> Q[qbase+l32][ks*16 + khi*8 + i]
  bf16x8 qf[4];
#pragma unroll
  for (int ks = 0; ks < 4; ++ks)
    qf[ks] = *(const bf16x8*)(qh + (size_t)(qbase + l32) * HDIM + ks * 16 + khi * 8);

  float lsum = 0.f;
  f32x16 o0, o1, sc;
#pragma unroll
  for (int i = 0; i < 16; ++i) { o0[i] = 0.f; o1[i] = 0.f; }

  // stage key-tile kb into buffer bidx: 1 K + 1 V DMA per wave (8 waves
  // cover 64 rows each of K and V^T)
  auto stage = [&](int bidx, int kb) {
    async16(&KV[bidx][wave * 512],        kh  + (size_t)(kb + wave * 8 + r8) * HDIM + jsw * 8);
    async16(&KV[bidx][4096 + wave * 512], vth + (size_t)(wave * 8 + r8) * SEQ + kb + jsw * 8);
  };

  const int krow = wh * 32 + l32;     // this wave's K row in the tile
  // S^T[32 keys(half wh)][32 q] = K_half * Q^T, one 32x32 acc over k=64
  auto qkt = [&](int bidx) {
#pragma unroll
    for (int i = 0; i < 16; ++i) sc[i] = 0.f;
    const u16* Kb = &KV[bidx][0];
#pragma unroll
    for (int ks = 0; ks < 4; ++ks) {
      bf16x8 kf = *(const bf16x8*)&Kb[krow * 64 + (((ks * 2 + khi) ^ e7) * 8)];
      sc = __builtin_amdgcn_mfma_f32_32x32x16_bf16(kf, qf[ks], sc, 0, 0, 0);
    }
  };

  // ---- prologue: stage tiles 0,1; wait tile 0 only; compute QK(0) ----
  stage(0, 0);
  stage(1, 64);
  asm volatile("s_waitcnt vmcnt(2)" ::: "memory");  // tile 0 landed, tile 1 in flight
  __syncthreads();
  qkt(0);

  int i0 = 0, i1 = 1, i2 = 2;   // rotating buffer indices: t, t+1, t+2
  for (int t = 0; t < 32; ++t) {
    if (t < 30) stage(i2, (t + 2) * 64);

    // ---- exp(t) + in-register transpose (8 pk2 + 4 permlane32_swap) ----
    // lane holds S^T[key = (r&3)+8*(r>>2)+4*khi (within half)][q = l32]
    bf16x8 pa[2];
    {
      float ls = 0.f;
#pragma unroll
      for (int s = 0; s < 2; ++s) {
        const float p0 = __builtin_amdgcn_exp2f(sc[8 * s + 0]);
        const float p1 = __builtin_amdgcn_exp2f(sc[8 * s + 1]);
        const float p2 = __builtin_amdgcn_exp2f(sc[8 * s + 2]);
        const float p3 = __builtin_amdgcn_exp2f(sc[8 * s + 3]);
        const float p4 = __builtin_amdgcn_exp2f(sc[8 * s + 4]);
        const float p5 = __builtin_amdgcn_exp2f(sc[8 * s + 5]);
        const float p6 = __builtin_amdgcn_exp2f(sc[8 * s + 6]);
        const float p7 = __builtin_amdgcn_exp2f(sc[8 * s + 7]);
        ls += ((p0 + p1) + (p2 + p3)) + ((p4 + p5) + (p6 + p7));
        unsigned u0 = pk2(p0, p1), u1 = pk2(p2, p3);
        unsigned v0 = pk2(p4, p5), v1 = pk2(p6, p7);
        pl32(u0, v0); pl32(u1, v1);
        union { uint4 uu; bf16x8 vv; } cvt;
        cvt.uu = uint4{u0, u1, v0, v1};
        pa[s] = cvt.vv;   // A-frag: P[q=l32][key_local = s*16 + 8*khi + i]
      }
      lsum += ls;
    }

    // ---- QK(t+1) + PV(t) at raised priority (T5) ----
    __builtin_amdgcn_s_setprio(1);
    if (t < 31) qkt(i1);

    // ---- PV(t): O_partial += P_half @ V_half (2 d-blocks x 2 k-steps) ----
    {
      const u16* Vb = &KV[i0][4096];
#pragma unroll
      for (int s = 0; s < 2; ++s) {
        const int c = wh * 4 + s * 2 + khi;   // logical 16B chunk in V^T row
        bf16x8 vf0 = *(const bf16x8*)&Vb[(l32) * 64 + ((c ^ e7) * 8)];
        bf16x8 vf1 = *(const bf16x8*)&Vb[(32 + l32) * 64 + ((c ^ e7) * 8)];
        o0 = __builtin_amdgcn_mfma_f32_32x32x16_bf16(pa[s], vf0, o0, 0, 0, 0);
        o1 = __builtin_amdgcn_mfma_f32_32x32x16_bf16(pa[s], vf1, o1, 0, 0, 0);
      }
    }
    __builtin_amdgcn_s_setprio(0);

    // bottom wait: drain tile t+1 (next to read), keep t+2's 2 DMAs in flight
    if (t < 30)      asm volatile("s_waitcnt vmcnt(2)" ::: "memory");
    else if (t < 31) asm volatile("s_waitcnt vmcnt(0)" ::: "memory");
    if (t < 31) __syncthreads();
    const int tmp = i0; i0 = i1; i1 = i2; i2 = tmp;
  }

  // ---- epilogue: merge key-half partials (wave pair 2qg, 2qg+1) ----
  // lsum: combine hi halves -> full 32-key-half sum for q=l32
  lsum += __shfl_xor(lsum, 32, 64);
  if (lane < 32) Lred[wave][l32] = lsum;

  __syncthreads();                      // all PV reads of KV done; Lred visible
  // ship the non-owned d-half (wh=0 keeps d0..31/o0, ships o1; wh=1 opposite)
  {
    float* myslot = (float*)&KV[0][0] + wave * 1024;
    const f32x16 ship = wh ? o0 : o1;
#pragma unroll
    for (int c = 0; c < 4; ++c) {
      f32x4 t;
      t[0] = ship[4 * c]; t[1] = ship[4 * c + 1];
      t[2] = ship[4 * c + 2]; t[3] = ship[4 * c + 3];
      *(f32x4*)&myslot[c * 256 + lane * 4] = t;
    }
  }
  __syncthreads();
  f32x16 own = wh ? o1 : o0;
  {
    const float* ps = (float*)&KV[0][0] + (wave ^ 1) * 1024;
#pragma unroll
    for (int c = 0; c < 4; ++c) {
      f32x4 t = *(const f32x4*)&ps[c * 256 + lane * 4];
      own[4 * c] += t[0]; own[4 * c + 1] += t[1];
      own[4 * c + 2] += t[2]; own[4 * c + 3] += t[3];
    }
  }

  // ---- normalize + store: lane holds O[q=(r&3)+8*(r>>2)+4*khi][d=wh*32+l32]
  {
    const int d = wh * 32 + l32;
    const float* lr0 = &Lred[qg * 2][0];
    const float* lr1 = &Lred[qg * 2 + 1][0];
#pragma unroll
    for (int r = 0; r < 16; ++r) {
      const int qv = (r & 3) + 8 * (r >> 2) + 4 * khi;
      const float inv = 1.f / fmaxf(lr0[qv] + lr1[qv], 1e-20f);
      out[((size_t)(b * SEQ + qbase + qv) * HEADS + h) * HDIM + d] = own[r] * inv;
    }
  }
}

extern "C" void kernel_launch(void* const* d_in, const int* in_sizes, int n_in,
                              void* d_out, int out_size, void* d_ws, size_t ws_size,
                              hipStream_t stream) {
  (void)in_sizes; (void)n_in; (void)out_size; (void)ws_size;
  const float* x  = (const float*)d_in[0];
  const float* Wq = (const float*)d_in[1];
  const float* bq = (const float*)d_in[2];
  const float* Wk = (const float*)d_in[3];
  const float* bk = (const float*)d_in[4];
  const float* Wv = (const float*)d_in[5];
  const float* bv = (const float*)d_in[6];
  float* out = (float*)d_out;

  u16* ws = (u16*)d_ws;
  const size_t XSZ = (size_t)BATCH * SEQ * DIM;           // 4M elems
  const size_t WSZ = (size_t)DIM * DIM;                   // 1M elems
  const size_t QSZ = (size_t)BATCH * HEADS * SEQ * HDIM;  // 4M elems
  u16* xbf   = ws;                       // bf16 x       [m][k]
  u16* wbf   = ws + XSZ;                 // bf16 Wq|Wk|Wv [n][k]
  u16* qbuf  = ws + XSZ + 3 * WSZ;       // bf16 Q(*QSCALE) [b][h][s][d]
  u16* kbuf  = qbuf + QSZ;               // bf16 K   [b][h][s][d]
  u16* vtbuf = kbuf + QSZ;               // bf16 V^T [b][h][d][s]

  convert_all<<<3584, 256, 0, stream>>>(x, Wq, Wk, Wv, xbf, wbf);

  qkv_gemm<<<1536, 256, 0, stream>>>(xbf, wbf, bq, bk, bv, qbuf, kbuf, vtbuf); // flat XCD-clustered

  attn<<<512, 512, 0, stream>>>(qbuf, kbuf, vtbuf, out);   // flat XCD-clustered grid
}

// Round 13
// 163.853 us; speedup vs baseline: 1.0839x; 1.0839x over previous
//
#include <hip/hip_runtime.h>
#include <hip/hip_bf16.h>

typedef unsigned short u16;
typedef __attribute__((ext_vector_type(8))) __bf16 bf16x8;
typedef __attribute__((ext_vector_type(4))) float f32x4;
typedef __attribute__((ext_vector_type(16))) float f32x16;
typedef __attribute__((ext_vector_type(8))) u16 u16x8;

#define BATCH 2
#define SEQ   2048
#define DIM   1024
#define HEADS 16
#define HDIM  64

// 0.125 (1/sqrt(64)) * log2(e): folded into Q so attn uses bare exp2
#define QSCALE 0.18033688011112042f

__device__ __forceinline__ float bf2f(u16 u) {
  union { unsigned int u; float f; } v; v.u = ((unsigned int)u) << 16; return v.f;
}
__device__ __forceinline__ u16 f2bf(float f) {
  union { float f; unsigned int u; } v; v.f = f;
  unsigned int r = v.u + 0x7fffu + ((v.u >> 16) & 1u);
  return (u16)(r >> 16);
}
// pack two fp32 -> bf16x2 (RNE) in one HW instr (v_cvt_pk_bf16_f32)
__device__ __forceinline__ unsigned int pk2(float a, float b) {
  union { __hip_bfloat162 h2; unsigned int u; } v;
  v.h2 = __float22bfloat162_rn(float2{a, b});
  return v.u;
}
// gfx950 two-register half-swap (VALU): a.lanes[32..63] <-> b.lanes[0..31]
__device__ __forceinline__ void pl32(unsigned &a, unsigned &b) {
  asm volatile("v_permlane32_swap_b32 %0, %1" : "+v"(a), "+v"(b));
}

// async global->LDS DMA, 16 B per lane; LDS dest = wave-uniform base + lane*16
__device__ __forceinline__ void async16(u16* lds, const u16* g) {
  __builtin_amdgcn_global_load_lds(
      (__attribute__((address_space(1))) void*)(void*)(g),
      (__attribute__((address_space(3))) void*)(lds), 16, 0, 0);
}

// ---------------------------------------------------------------------------
// Kernel 0: one-shot fp32 -> bf16 (RNE) conversion of x, Wq, Wk, Wv.
// ---------------------------------------------------------------------------
#define XG  524288   /* x groups of 8 */
#define WG  131072   /* per-W groups of 8 */
extern "C" __global__ __launch_bounds__(256)
void convert_all(const float* __restrict__ x,  const float* __restrict__ wq,
                 const float* __restrict__ wk, const float* __restrict__ wv,
                 u16* __restrict__ xbf, u16* __restrict__ wbf)
{
  const int g = blockIdx.x * 256 + threadIdx.x;
  const float* src; u16* dst; size_t off;
  if (g < XG)               { src = x;  dst = xbf;                 off = (size_t)g; }
  else if (g < XG + WG)     { src = wq; dst = wbf;                 off = (size_t)(g - XG); }
  else if (g < XG + 2 * WG) { src = wk; dst = wbf + DIM * DIM;     off = (size_t)(g - XG - WG); }
  else                      { src = wv; dst = wbf + 2 * DIM * DIM; off = (size_t)(g - XG - 2 * WG); }
  f32x4 a = *(const f32x4*)(src + off * 8);
  f32x4 b = *(const f32x4*)(src + off * 8 + 4);
  u16x8 o;
#pragma unroll
  for (int i = 0; i < 4; ++i) { o[i] = f2bf(a[i]); o[4 + i] = f2bf(b[i]); }
  *(u16x8*)(dst + off * 8) = o;
}

// ---------------------------------------------------------------------------
// Kernel 1: QKV projection — REVERTED to round-17/R11 form (best measured:
// qkv <= 50.7 in R11). R12's 128x64 tiling regressed (occupancy 14->30% and
// FETCH 68.7->28.7 MB yet dur unchanged — qkv is chain-bound per iteration,
// not occupancy- or drain-bound; smaller tiles worsened MFMA:DS ratio).
// 128x128 tile, 2D XCD-clustered flat grid, triple-buffered pipelined
// K-loop (bottom wait vmcnt(4)), setprio, chunk swizzle, packed V^T store.
// grid: flat 768  block: 256
// which==0 -> Q(*QSCALE) [b][h][s][d]; 1 -> K [b][h][s][d]; 2 -> V^T [b][h][d][s]
// ---------------------------------------------------------------------------
extern "C" __global__ __launch_bounds__(256)
void qkv_gemm(const u16* __restrict__ xbf, const u16* __restrict__ wbf,
              const float* __restrict__ bq, const float* __restrict__ bk,
              const float* __restrict__ bv,
              u16* __restrict__ qo, u16* __restrict__ ko, u16* __restrict__ vto)
{
  __shared__ alignas(16) u16 Albs[3][128 * 32];  // 24 KB
  __shared__ alignas(16) u16 Blbs[3][128 * 32];  // 24 KB

  // XCD-clustered decode: XCD p = wg&7 owns m-group p>>1 (8 panels) x
  // n-group p&1 (4 blocks) x all 3 which; within patch which-major.
  const int wg = blockIdx.x;           // 0..767
  const int p  = wg & 7;
  const int q  = wg >> 3;              // 0..95
  const int which = q >> 5;            // 0..2
  const int r  = q & 31;               // 0..31: 8 m x 4 n
  const int mBase = ((p >> 1) * 8 + (r >> 2)) * 128;
  const int nBase = ((p & 1) * 4 + (r & 3)) * 128;

  const u16* Wb = wbf + (size_t)which * DIM * DIM;
  const float* bias = (which == 0) ? bq : (which == 1) ? bk : bv;

  const int lane = threadIdx.x & 63;
  const int wave = threadIdx.x >> 6;
  const int l16  = lane & 15;
  const int quad = lane >> 4;
  const int lrow = lane >> 2;                      // 16 rows per DMA instr
  const int lcol = ((lane & 3) ^ ((lane >> 3) & 3)) * 8;  // swizzled src chunk
  const int rkey = (l16 >> 1) & 3;                 // read-side chunk XOR key

  const int mw = (wave >> 1) * 64;   // wave's 64x64 quadrant
  const int nw = (wave & 1) * 64;

  f32x4 acc[4][4] = {};

  // stage K-tile kt (32 wide) into buffer bidx: 4 DMA instrs per wave
  auto stage = [&](int bidx, int kt) {
    const int k0 = kt * 32;
#pragma unroll
    for (int pp = 0; pp < 2; ++pp) {
      const int r16 = wave * 2 + pp;                 // wave-uniform
      const int row = r16 * 16 + lrow;
      async16(&Albs[bidx][r16 * 512], xbf + (size_t)(mBase + row) * DIM + k0 + lcol);
      async16(&Blbs[bidx][r16 * 512], Wb  + (size_t)(nBase + row) * DIM + k0 + lcol);
    }
  };
  // one BK=32 step of MFMA from buffer bidx
  auto comp = [&](int bidx) {
    bf16x8 af[4], bfr[4];
#pragma unroll
    for (int i = 0; i < 4; ++i) {
      af[i]  = *(const bf16x8*)&Albs[bidx][(mw + i * 16 + l16) * 32 + ((quad ^ rkey) * 8)];
      bfr[i] = *(const bf16x8*)&Blbs[bidx][(nw + i * 16 + l16) * 32 + ((quad ^ rkey) * 8)];
    }
    __builtin_amdgcn_s_setprio(1);
#pragma unroll
    for (int mi = 0; mi < 4; ++mi)
#pragma unroll
      for (int ni = 0; ni < 4; ++ni)
        acc[mi][ni] = __builtin_amdgcn_mfma_f32_16x16x32_bf16(af[mi], bfr[ni], acc[mi][ni], 0, 0, 0);
    __builtin_amdgcn_s_setprio(0);
  };

  // ---- prologue: stage tiles 0,1; wait tile 0 only (tile 1 in flight) ----
  stage(0, 0);
  stage(1, 1);
  asm volatile("s_waitcnt vmcnt(4)" ::: "memory");
  __syncthreads();

  int i0 = 0, i1 = 1, i2 = 2;   // rotating buffers: tile t, t+1, t+2
  for (int t = 0; t < 32; ++t) {
    if (t < 30) stage(i2, t + 2);
    comp(i0);
    // bottom wait: tile t+1 landed, keep tile t+2's 4 DMAs in flight
    if (t < 30)      asm volatile("s_waitcnt vmcnt(4)" ::: "memory");
    else if (t < 31) asm volatile("s_waitcnt vmcnt(0)" ::: "memory");
    if (t < 31) __syncthreads();
    const int tmp = i0; i0 = i1; i1 = i2; i2 = tmp;
  }

  const float oscale = (which == 0) ? QSCALE : 1.0f;
#pragma unroll
  for (int ni = 0; ni < 4; ++ni) {
    const int n = nBase + nw + ni * 16 + l16;   // C/D col = lane&15
    const float bval = bias[n];
    const int h = n >> 6, d = n & 63;
#pragma unroll
    for (int mi = 0; mi < 4; ++mi) {
      const int m0 = mBase + mw + mi * 16 + quad * 4;  // row = quad*4+r
      if (which == 2) {
        // s = m0..m0+3 consecutive -> one 8 B store of 4 packed bf16
        const int bi = m0 >> 11, s = m0 & 2047;
        uint2 pkv;
        pkv.x = pk2(acc[mi][ni][0] + bval, acc[mi][ni][1] + bval);
        pkv.y = pk2(acc[mi][ni][2] + bval, acc[mi][ni][3] + bval);
        *(uint2*)&vto[((size_t)(bi * HEADS + h) * HDIM + d) * SEQ + s] = pkv;
      } else {
        u16* dst = (which == 0) ? qo : ko;
#pragma unroll
        for (int rr = 0; rr < 4; ++rr) {
          const int m = m0 + rr;
          const int bi = m >> 11, s = m & 2047;
          dst[((size_t)(bi * HEADS + h) * SEQ + s) * HDIM + d] =
              f2bf((acc[mi][ni][rr] + bval) * oscale);
        }
      }
    }
  }
}

// ---------------------------------------------------------------------------
// Kernel 2: flash attention — round-19: R8 structure + MFMA-ones lsum.
// attn counters (stable across runs): VALUBusy 52% = the biggest pipe.
// Per wave-iter VALU ~120 cyc incl. 15 serial adds for lsum (loop-carried
// chain). Replace the scalar reduction with lsum[q] = P @ ones: 2 extra
// 32x32x16 MFMAs/iter into lacc (A-frags pa[s] already exist for PV; B =
// constant ones). MFMA pipe is only 27% busy — free capacity. Epilogue:
// C[row][col] is col-invariant, so lanes l32==0 (khi=0/1) hold complete
// disjoint row sets {(r&3)+8(r>>2)+4khi} and write Lred[wave][row]
// directly; the shfl_xor combine is deleted.
// Rest unchanged: 32x32x16 MFMA, key-half wave split, 8 waves, triple-
// buffered K/V, permlane transpose, XCD-clustered grid, setprio.
// grid: flat 512  block: 512
// ---------------------------------------------------------------------------
extern "C" __global__ __launch_bounds__(512)
void attn(const u16* __restrict__ q, const u16* __restrict__ k,
          const u16* __restrict__ vt, float* __restrict__ out)
{
  __shared__ alignas(16) u16 KV[3][8192];   // per buf: K [0,4096), V [4096,8192)
  __shared__ float Lred[8][32];             // per-wave lsum, 1 KB

  const int lane = threadIdx.x & 63;
  const int wave = threadIdx.x >> 6;  // 0..7
  const int qg   = wave >> 1;         // q-group (32 rows)
  const int wh   = wave & 1;          // key half: keys wh*32..wh*32+31
  const int l32  = lane & 31;
  const int khi  = lane >> 5;         // hi bit of lane
  const int e7   = lane & 7;          // row&7 for K/V fragment reads
  const int r8   = lane >> 3;         // DMA: row within 8-row group
  const int sl   = lane & 7;          // DMA: 16B slot within row
  const int jsw  = sl ^ (r8 & 7);     // swizzled source chunk for DMA

  // XCD-clustered decode: wgid = (hb&7) + 8*qb + 128*(hb>>3)
  const int wg = blockIdx.x;
  const int hb = (wg & 7) | ((wg >> 7) << 3);   // h + 16*b, 0..31
  const int qb = (wg >> 3) & 15;
  const int h  = hb & 15;
  const int b  = hb >> 4;
  const int qbase = qb * 128 + qg * 32;

  const u16* qh  = q  + (size_t)(b * HEADS + h) * SEQ * HDIM;
  const u16* kh  = k  + (size_t)(b * HEADS + h) * SEQ * HDIM;
  const u16* vth = vt + (size_t)(b * HEADS + h) * HDIM * SEQ;

  // constant ones B-frag (bf16 1.0 = 0x3F80) for the lsum MFMA
  union { u16x8 u; bf16x8 v; } onesu;
#pragma unroll
  for (int i = 0; i < 8; ++i) onesu.u[i] = 0x3F80;
  const bf16x8 ones = onesu.v;

  // Q B-frags (32x32x16): lane -> Q[qbase+l32][ks*16 + khi*8 + i]
  bf16x8 qf[4];
#pragma unroll
  for (int ks = 0; ks < 4; ++ks)
    qf[ks] = *(const bf16x8*)(qh + (size_t)(qbase + l32) * HDIM + ks * 16 + khi * 8);

  f32x16 o0, o1, sc, lacc;
#pragma unroll
  for (int i = 0; i < 16; ++i) { o0[i] = 0.f; o1[i] = 0.f; lacc[i] = 0.f; }

  // stage key-tile kb into buffer bidx: 1 K + 1 V DMA per wave (8 waves
  // cover 64 rows each of K and V^T)
  auto stage = [&](int bidx, int kb) {
    async16(&KV[bidx][wave * 512],        kh  + (size_t)(kb + wave * 8 + r8) * HDIM + jsw * 8);
    async16(&KV[bidx][4096 + wave * 512], vth + (size_t)(wave * 8 + r8) * SEQ + kb + jsw * 8);
  };

  const int krow = wh * 32 + l32;     // this wave's K row in the tile
  // S^T[32 keys(half wh)][32 q] = K_half * Q^T, one 32x32 acc over k=64
  auto qkt = [&](int bidx) {
#pragma unroll
    for (int i = 0; i < 16; ++i) sc[i] = 0.f;
    const u16* Kb = &KV[bidx][0];
#pragma unroll
    for (int ks = 0; ks < 4; ++ks) {
      bf16x8 kf = *(const bf16x8*)&Kb[krow * 64 + (((ks * 2 + khi) ^ e7) * 8)];
      sc = __builtin_amdgcn_mfma_f32_32x32x16_bf16(kf, qf[ks], sc, 0, 0, 0);
    }
  };

  // ---- prologue: stage tiles 0,1; wait tile 0 only; compute QK(0) ----
  stage(0, 0);
  stage(1, 64);
  asm volatile("s_waitcnt vmcnt(2)" ::: "memory");  // tile 0 landed, tile 1 in flight
  __syncthreads();
  qkt(0);

  int i0 = 0, i1 = 1, i2 = 2;   // rotating buffer indices: t, t+1, t+2
  for (int t = 0; t < 32; ++t) {
    if (t < 30) stage(i2, (t + 2) * 64);

    // ---- exp(t) + in-register transpose (8 pk2 + 4 permlane32_swap) ----
    // lane holds S^T[key = (r&3)+8*(r>>2)+4*khi (within half)][q = l32]
    bf16x8 pa[2];
#pragma unroll
    for (int s = 0; s < 2; ++s) {
      const float p0 = __builtin_amdgcn_exp2f(sc[8 * s + 0]);
      const float p1 = __builtin_amdgcn_exp2f(sc[8 * s + 1]);
      const float p2 = __builtin_amdgcn_exp2f(sc[8 * s + 2]);
      const float p3 = __builtin_amdgcn_exp2f(sc[8 * s + 3]);
      const float p4 = __builtin_amdgcn_exp2f(sc[8 * s + 4]);
      const float p5 = __builtin_amdgcn_exp2f(sc[8 * s + 5]);
      const float p6 = __builtin_amdgcn_exp2f(sc[8 * s + 6]);
      const float p7 = __builtin_amdgcn_exp2f(sc[8 * s + 7]);
      unsigned u0 = pk2(p0, p1), u1 = pk2(p2, p3);
      unsigned v0 = pk2(p4, p5), v1 = pk2(p6, p7);
      pl32(u0, v0); pl32(u1, v1);
      union { uint4 uu; bf16x8 vv; } cvt;
      cvt.uu = uint4{u0, u1, v0, v1};
      pa[s] = cvt.vv;   // A-frag: P[q=l32][key_local = s*16 + 8*khi + i]
    }

    // ---- QK(t+1) + PV(t) + lsum MFMA at raised priority (T5) ----
    __builtin_amdgcn_s_setprio(1);
    if (t < 31) qkt(i1);

    // ---- PV(t): O_partial += P_half @ V_half; lacc += P_half @ ones ----
    {
      const u16* Vb = &KV[i0][4096];
#pragma unroll
      for (int s = 0; s < 2; ++s) {
        const int c = wh * 4 + s * 2 + khi;   // logical 16B chunk in V^T row
        bf16x8 vf0 = *(const bf16x8*)&Vb[(l32) * 64 + ((c ^ e7) * 8)];
        bf16x8 vf1 = *(const bf16x8*)&Vb[(32 + l32) * 64 + ((c ^ e7) * 8)];
        o0 = __builtin_amdgcn_mfma_f32_32x32x16_bf16(pa[s], vf0, o0, 0, 0, 0);
        o1 = __builtin_amdgcn_mfma_f32_32x32x16_bf16(pa[s], vf1, o1, 0, 0, 0);
        lacc = __builtin_amdgcn_mfma_f32_32x32x16_bf16(pa[s], ones, lacc, 0, 0, 0);
      }
    }
    __builtin_amdgcn_s_setprio(0);

    // bottom wait: drain tile t+1 (next to read), keep t+2's 2 DMAs in flight
    if (t < 30)      asm volatile("s_waitcnt vmcnt(2)" ::: "memory");
    else if (t < 31) asm volatile("s_waitcnt vmcnt(0)" ::: "memory");
    if (t < 31) __syncthreads();
    const int tmp = i0; i0 = i1; i1 = i2; i2 = tmp;
  }

  // ---- epilogue: publish lsum (col-invariant rowsums; lanes l32==0 of
  // each khi hold complete disjoint row sets), merge key-half partials ----
  if (l32 == 0) {
#pragma unroll
    for (int r = 0; r < 16; ++r)
      Lred[wave][(r & 3) + 8 * (r >> 2) + 4 * khi] = lacc[r];
  }

  __syncthreads();                      // all PV reads of KV done; Lred visible
  // ship the non-owned d-half (wh=0 keeps d0..31/o0, ships o1; wh=1 opposite)
  {
    float* myslot = (float*)&KV[0][0] + wave * 1024;
    const f32x16 ship = wh ? o0 : o1;
#pragma unroll
    for (int c = 0; c < 4; ++c) {
      f32x4 t;
      t[0] = ship[4 * c]; t[1] = ship[4 * c + 1];
      t[2] = ship[4 * c + 2]; t[3] = ship[4 * c + 3];
      *(f32x4*)&myslot[c * 256 + lane * 4] = t;
    }
  }
  __syncthreads();
  f32x16 own = wh ? o1 : o0;
  {
    const float* ps = (float*)&KV[0][0] + (wave ^ 1) * 1024;
#pragma unroll
    for (int c = 0; c < 4; ++c) {
      f32x4 t = *(const f32x4*)&ps[c * 256 + lane * 4];
      own[4 * c] += t[0]; own[4 * c + 1] += t[1];
      own[4 * c + 2] += t[2]; own[4 * c + 3] += t[3];
    }
  }

  // ---- normalize + store: lane holds O[q=(r&3)+8*(r>>2)+4*khi][d=wh*32+l32]
  {
    const int d = wh * 32 + l32;
    const float* lr0 = &Lred[qg * 2][0];
    const float* lr1 = &Lred[qg * 2 + 1][0];
#pragma unroll
    for (int r = 0; r < 16; ++r) {
      const int qv = (r & 3) + 8 * (r >> 2) + 4 * khi;
      const float inv = 1.f / fmaxf(lr0[qv] + lr1[qv], 1e-20f);
      out[((size_t)(b * SEQ + qbase + qv) * HEADS + h) * HDIM + d] = own[r] * inv;
    }
  }
}

extern "C" void kernel_launch(void* const* d_in, const int* in_sizes, int n_in,
                              void* d_out, int out_size, void* d_ws, size_t ws_size,
                              hipStream_t stream) {
  (void)in_sizes; (void)n_in; (void)out_size; (void)ws_size;
  const float* x  = (const float*)d_in[0];
  const float* Wq = (const float*)d_in[1];
  const float* bq = (const float*)d_in[2];
  const float* Wk = (const float*)d_in[3];
  const float* bk = (const float*)d_in[4];
  const float* Wv = (const float*)d_in[5];
  const float* bv = (const float*)d_in[6];
  float* out = (float*)d_out;

  u16* ws = (u16*)d_ws;
  const size_t XSZ = (size_t)BATCH * SEQ * DIM;           // 4M elems
  const size_t WSZ = (size_t)DIM * DIM;                   // 1M elems
  const size_t QSZ = (size_t)BATCH * HEADS * SEQ * HDIM;  // 4M elems
  u16* xbf   = ws;                       // bf16 x       [m][k]
  u16* wbf   = ws + XSZ;                 // bf16 Wq|Wk|Wv [n][k]
  u16* qbuf  = ws + XSZ + 3 * WSZ;       // bf16 Q(*QSCALE) [b][h][s][d]
  u16* kbuf  = qbuf + QSZ;               // bf16 K   [b][h][s][d]
  u16* vtbuf = kbuf + QSZ;               // bf16 V^T [b][h][d][s]

  convert_all<<<3584, 256, 0, stream>>>(x, Wq, Wk, Wv, xbf, wbf);

  qkv_gemm<<<768, 256, 0, stream>>>(xbf, wbf, bq, bk, bv, qbuf, kbuf, vtbuf);  // flat XCD-clustered

  attn<<<512, 512, 0, stream>>>(qbuf, kbuf, vtbuf, out);   // flat XCD-clustered grid
}